// Round 3
// baseline (294.425 us; speedup 1.0000x reference)
//
#include <hip/hip_runtime.h>
#include <math.h>

#define N_NUC 256
#define N_NB  1024
#define N_ENV 8
#define F0    32
#define F1    16
#define FEAT  256
#define CUTOFF 5.0f

constexpr int NP = N_NUC * N_NB;              // 262144 pairs
constexpr int PW = 32;                        // pairs per wave
constexpr int NBLOCKS = NP / PW / 4;          // 2048 blocks x 4 waves

__device__ __forceinline__ float rl(float x, int i) {
    return __int_as_float(__builtin_amdgcn_readlane(__float_as_int(x), i));
}

// ============ Kernel 1: per-pair beta[16] (cut folded) + inp[4] -> ws ============
__global__ __launch_bounds__(256) void moon_k1(
    const float* __restrict__ r_nb_ne, const float* __restrict__ R,
    const float* __restrict__ ne_scales, const float* __restrict__ ne_kernel,
    const float* __restrict__ ne_bias, const float* __restrict__ env_weight,
    const float* __restrict__ W_beta,
    float* __restrict__ betaW,            // (NP,16)
    float* __restrict__ inpW)             // (NP,4)
{
    const int tid  = threadIdx.x;
    const int lane = tid & 63;
    const int wid  = tid >> 6;
    const int w    = blockIdx.x * 4 + wid;
    const int n    = w >> 5;
    const int e00  = (w & 31) * PW;
    const int k    = lane & 31;
    const int ph   = lane >> 5;
    const int j    = lane & 15;

    const float Rx = R[n * 3 + 0], Ry = R[n * 3 + 1], Rz = R[n * 3 + 2];
    const float K0 = ne_kernel[n * 128 + 0 * 32 + k];
    const float K1 = ne_kernel[n * 128 + 1 * 32 + k];
    const float K2 = ne_kernel[n * 128 + 2 * 32 + k];
    const float K3 = ne_kernel[n * 128 + 3 * 32 + k];
    const float bk = ne_bias[n * 32 + k];
    float ew[N_ENV], sc[N_ENV];
    #pragma unroll
    for (int v = 0; v < N_ENV; ++v) ew[v] = env_weight[v * 32 + k];
    #pragma unroll
    for (int v = 0; v < N_ENV; ++v) sc[v] = ne_scales[n * N_ENV + v];
    float wb_col[F0];
    #pragma unroll
    for (int kk = 0; kk < F0; ++kk) wb_col[kk] = W_beta[kk * F1 + j];

    float rx, ry, rz;
    {
        const size_t pr = ((size_t)n * N_NB + e00 + ph) * 3;
        rx = r_nb_ne[pr + 0]; ry = r_nb_ne[pr + 1]; rz = r_nb_ne[pr + 2];
    }

    for (int it = 0; it < PW / 2; ++it) {
        const float cx = rx, cy = ry, cz = rz;
        if (it + 1 < PW / 2) {
            const size_t pr = ((size_t)n * N_NB + e00 + (it + 1) * 2 + ph) * 3;
            rx = r_nb_ne[pr + 0]; ry = r_nb_ne[pr + 1]; rz = r_nb_ne[pr + 2];
        }
        const float dx = cx - Rx, dy = cy - Ry, dz = cz - Rz;
        const float d  = sqrtf(dx * dx + dy * dy + dz * dz);
        float env = 0.f;
        #pragma unroll
        for (int v = 0; v < N_ENV; ++v) env += __expf(-d * sc[v]) * ew[v];
        const float pre = d * K0 + dx * K1 + dy * K2 + dz * K3 + bk;
        const float ex  = __expf(2.f * pre);
        const float hv  = (1.f - __fdividef(2.f, ex + 1.f)) * env;

        const float xcv = d * (1.0f / CUTOFF);
        const float om  = 1.0f - xcv;
        const float cut = (xcv < 1.0f) ? om * om * (1.0f + 2.0f * xcv) : 0.0f;
        const float l   = log1pf(d);
        const float li  = __fdividef(l, d);

        float acc0 = 0.f, acc1 = 0.f;
        #pragma unroll
        for (int kk = 0; kk < F0; ++kk) {
            const float s0 = rl(hv, kk);
            const float s1 = rl(hv, kk + 32);
            acc0 += s0 * wb_col[kk];
            acc1 += s1 * wb_col[kk];
        }
        const float cut0 = rl(cut, 0), cut1 = rl(cut, 32);
        const float betab = ((lane >> 4) & 1) ? acc1 * cut1 : acc0 * cut0;

        const int pairBase = n * N_NB + e00 + it * 2;   // pair0 index
        if (lane < 32)
            betaW[(size_t)pairBase * 16 + lane] = betab;  // [p0 j0..15][p1 j0..15]
        if (k == 0) {
            float4 ip = {l, dx * li, dy * li, dz * li};
            *reinterpret_cast<float4*>(&inpW[(size_t)(pairBase + ph) * 4]) = ip;
        }
    }
}

// ============ Kernel 2: stream FEAT — pure BW ============
__global__ __launch_bounds__(256) void moon_k2(
    const float* __restrict__ betaW, const float* __restrict__ inpW,
    const float* __restrict__ W_gamma, const float* __restrict__ W_edge,
    const float* __restrict__ b_edge, const float* __restrict__ z_n,
    float* __restrict__ out)
{
    const int tid  = threadIdx.x;
    const int lane = tid & 63;
    const int wid  = tid >> 6;
    const int w    = blockIdx.x * 4 + wid;
    const int n    = w >> 5;                 // 32 waves per nucleus
    const int pair0 = w * PW;
    const int f0   = lane * 4;

    float4 wg4[F1];
    #pragma unroll
    for (int jj = 0; jj < F1; ++jj)
        wg4[jj] = *reinterpret_cast<const float4*>(&W_gamma[jj * FEAT + f0]);
    float4 we4[4];
    #pragma unroll
    for (int c = 0; c < 4; ++c)
        we4[c] = *reinterpret_cast<const float4*>(&W_edge[c * FEAT + f0]);
    float4 zb4 = *reinterpret_cast<const float4*>(&z_n[n * FEAT + f0]);
    {
        float4 b4 = *reinterpret_cast<const float4*>(&b_edge[f0]);
        zb4.x += b4.x; zb4.y += b4.y; zb4.z += b4.z; zb4.w += b4.w;
    }

    float* __restrict__ gamma_out = out;
    float* __restrict__ edge_out  = out + (size_t)NP * FEAT;

    // prefetch pair0's interface
    float4 nb0 = *reinterpret_cast<const float4*>(&betaW[(size_t)pair0 * 16 + 0]);
    float4 nb1 = *reinterpret_cast<const float4*>(&betaW[(size_t)pair0 * 16 + 4]);
    float4 nb2 = *reinterpret_cast<const float4*>(&betaW[(size_t)pair0 * 16 + 8]);
    float4 nb3 = *reinterpret_cast<const float4*>(&betaW[(size_t)pair0 * 16 + 12]);
    float4 nip = *reinterpret_cast<const float4*>(&inpW[(size_t)pair0 * 4]);

    for (int p = 0; p < PW; ++p) {
        const int pair = pair0 + p;
        const float4 b0 = nb0, b1 = nb1, b2 = nb2, b3 = nb3, ip = nip;
        if (p + 1 < PW) {
            const size_t nb = (size_t)(pair + 1);
            nb0 = *reinterpret_cast<const float4*>(&betaW[nb * 16 + 0]);
            nb1 = *reinterpret_cast<const float4*>(&betaW[nb * 16 + 4]);
            nb2 = *reinterpret_cast<const float4*>(&betaW[nb * 16 + 8]);
            nb3 = *reinterpret_cast<const float4*>(&betaW[nb * 16 + 12]);
            nip = *reinterpret_cast<const float4*>(&inpW[nb * 4]);
        }
        const float bj[16] = {b0.x, b0.y, b0.z, b0.w, b1.x, b1.y, b1.z, b1.w,
                              b2.x, b2.y, b2.z, b2.w, b3.x, b3.y, b3.z, b3.w};
        float4 gam = {0.f, 0.f, 0.f, 0.f};
        #pragma unroll
        for (int jj = 0; jj < F1; ++jj) {
            gam.x += bj[jj] * wg4[jj].x;
            gam.y += bj[jj] * wg4[jj].y;
            gam.z += bj[jj] * wg4[jj].z;
            gam.w += bj[jj] * wg4[jj].w;
        }
        float4 ed;
        ed.x = ip.x * we4[0].x + ip.y * we4[1].x + ip.z * we4[2].x + ip.w * we4[3].x + zb4.x;
        ed.y = ip.x * we4[0].y + ip.y * we4[1].y + ip.z * we4[2].y + ip.w * we4[3].y + zb4.y;
        ed.z = ip.x * we4[0].z + ip.y * we4[1].z + ip.z * we4[2].z + ip.w * we4[3].z + zb4.z;
        ed.w = ip.x * we4[0].w + ip.y * we4[1].w + ip.z * we4[2].w + ip.w * we4[3].w + zb4.w;
        const size_t base = (size_t)pair * FEAT + f0;
        *reinterpret_cast<float4*>(&gamma_out[base]) = gam;
        *reinterpret_cast<float4*>(&edge_out[base])  = ed;
    }
}

// ============ Fallback: R2 monolithic (if ws too small) ============
__global__ __launch_bounds__(256) void moon_mono(
    const float* __restrict__ r_nb_ne, const float* __restrict__ R,
    const float* __restrict__ ne_scales, const float* __restrict__ ne_kernel,
    const float* __restrict__ ne_bias, const float* __restrict__ env_weight,
    const float* __restrict__ W_beta, const float* __restrict__ W_gamma,
    const float* __restrict__ W_edge, const float* __restrict__ b_edge,
    const float* __restrict__ z_n, float* __restrict__ out)
{
    const int tid  = threadIdx.x;
    const int lane = tid & 63;
    const int wid  = tid >> 6;
    const int w    = blockIdx.x * 4 + wid;
    const int n    = w >> 5;
    const int e00  = (w & 31) * PW;
    const int k    = lane & 31;
    const int ph   = lane >> 5;
    const int j    = lane & 15;
    const int f0   = lane * 4;

    const float Rx = R[n * 3 + 0], Ry = R[n * 3 + 1], Rz = R[n * 3 + 2];
    const float K0 = ne_kernel[n * 128 + 0 * 32 + k];
    const float K1 = ne_kernel[n * 128 + 1 * 32 + k];
    const float K2 = ne_kernel[n * 128 + 2 * 32 + k];
    const float K3 = ne_kernel[n * 128 + 3 * 32 + k];
    const float bk = ne_bias[n * 32 + k];
    float ew[N_ENV], sc[N_ENV];
    #pragma unroll
    for (int v = 0; v < N_ENV; ++v) ew[v] = env_weight[v * 32 + k];
    #pragma unroll
    for (int v = 0; v < N_ENV; ++v) sc[v] = ne_scales[n * N_ENV + v];
    float wb_col[F0];
    #pragma unroll
    for (int kk = 0; kk < F0; ++kk) wb_col[kk] = W_beta[kk * F1 + j];
    float4 wg4[F1];
    #pragma unroll
    for (int jj = 0; jj < F1; ++jj)
        wg4[jj] = *reinterpret_cast<const float4*>(&W_gamma[jj * FEAT + f0]);
    float4 we4[4];
    #pragma unroll
    for (int c = 0; c < 4; ++c)
        we4[c] = *reinterpret_cast<const float4*>(&W_edge[c * FEAT + f0]);
    float4 zb4 = *reinterpret_cast<const float4*>(&z_n[n * FEAT + f0]);
    {
        float4 b4 = *reinterpret_cast<const float4*>(&b_edge[f0]);
        zb4.x += b4.x; zb4.y += b4.y; zb4.z += b4.z; zb4.w += b4.w;
    }
    float* __restrict__ gamma_out = out;
    float* __restrict__ edge_out  = out + (size_t)NP * FEAT;

    float rx, ry, rz;
    {
        const size_t pr = ((size_t)n * N_NB + e00 + ph) * 3;
        rx = r_nb_ne[pr + 0]; ry = r_nb_ne[pr + 1]; rz = r_nb_ne[pr + 2];
    }
    for (int it = 0; it < PW / 2; ++it) {
        const float cx = rx, cy = ry, cz = rz;
        if (it + 1 < PW / 2) {
            const size_t pr = ((size_t)n * N_NB + e00 + (it + 1) * 2 + ph) * 3;
            rx = r_nb_ne[pr + 0]; ry = r_nb_ne[pr + 1]; rz = r_nb_ne[pr + 2];
        }
        const float dx = cx - Rx, dy = cy - Ry, dz = cz - Rz;
        const float d  = sqrtf(dx * dx + dy * dy + dz * dz);
        float env = 0.f;
        #pragma unroll
        for (int v = 0; v < N_ENV; ++v) env += __expf(-d * sc[v]) * ew[v];
        const float pre = d * K0 + dx * K1 + dy * K2 + dz * K3 + bk;
        const float ex  = __expf(2.f * pre);
        const float hv  = (1.f - __fdividef(2.f, ex + 1.f)) * env;
        const float xcv = d * (1.0f / CUTOFF);
        const float om  = 1.0f - xcv;
        const float cut = (xcv < 1.0f) ? om * om * (1.0f + 2.0f * xcv) : 0.0f;
        const float l   = log1pf(d);
        const float li  = __fdividef(l, d);
        const float i1  = dx * li, i2 = dy * li, i3 = dz * li;

        float acc0 = 0.f, acc1 = 0.f;
        #pragma unroll
        for (int kk = 0; kk < F0; ++kk) {
            const float s0 = rl(hv, kk);
            const float s1 = rl(hv, kk + 32);
            acc0 += s0 * wb_col[kk];
            acc1 += s1 * wb_col[kk];
        }
        const float cut0 = rl(cut, 0), cut1 = rl(cut, 32);
        const float betab = ((lane >> 4) & 1) ? acc1 * cut1 : acc0 * cut0;

        #pragma unroll
        for (int p = 0; p < 2; ++p) {
            const int ep = e00 + it * 2 + p;
            const size_t base = ((size_t)n * N_NB + ep) * FEAT + f0;
            float4 gam = {0.f, 0.f, 0.f, 0.f};
            #pragma unroll
            for (int jj = 0; jj < F1; ++jj) {
                const float b = rl(betab, p * 16 + jj);
                gam.x += b * wg4[jj].x;
                gam.y += b * wg4[jj].y;
                gam.z += b * wg4[jj].z;
                gam.w += b * wg4[jj].w;
            }
            const float i0s = rl(l,  p * 32);
            const float i1s = rl(i1, p * 32);
            const float i2s = rl(i2, p * 32);
            const float i3s = rl(i3, p * 32);
            float4 ed;
            ed.x = i0s * we4[0].x + i1s * we4[1].x + i2s * we4[2].x + i3s * we4[3].x + zb4.x;
            ed.y = i0s * we4[0].y + i1s * we4[1].y + i2s * we4[2].y + i3s * we4[3].y + zb4.y;
            ed.z = i0s * we4[0].z + i1s * we4[1].z + i2s * we4[2].z + i3s * we4[3].z + zb4.z;
            ed.w = i0s * we4[0].w + i1s * we4[1].w + i2s * we4[2].w + i3s * we4[3].w + zb4.w;
            *reinterpret_cast<float4*>(&gamma_out[base]) = gam;
            *reinterpret_cast<float4*>(&edge_out[base])  = ed;
        }
    }
}

extern "C" void kernel_launch(void* const* d_in, const int* in_sizes, int n_in,
                              void* d_out, int out_size, void* d_ws, size_t ws_size,
                              hipStream_t stream) {
    const float* r_nb_ne    = (const float*)d_in[0];
    const float* R          = (const float*)d_in[1];
    const float* ne_scales  = (const float*)d_in[2];
    const float* ne_kernel  = (const float*)d_in[3];
    const float* ne_bias    = (const float*)d_in[4];
    const float* env_weight = (const float*)d_in[5];
    const float* W_beta     = (const float*)d_in[6];
    const float* W_gamma    = (const float*)d_in[7];
    const float* W_edge     = (const float*)d_in[8];
    const float* b_edge     = (const float*)d_in[9];
    const float* z_n        = (const float*)d_in[10];
    float* out = (float*)d_out;

    const size_t need = (size_t)NP * 20 * sizeof(float);  // 16 beta + 4 inp
    if (ws_size >= need) {
        float* betaW = (float*)d_ws;
        float* inpW  = betaW + (size_t)NP * 16;
        moon_k1<<<NBLOCKS, 256, 0, stream>>>(
            r_nb_ne, R, ne_scales, ne_kernel, ne_bias, env_weight, W_beta,
            betaW, inpW);
        moon_k2<<<NBLOCKS, 256, 0, stream>>>(
            betaW, inpW, W_gamma, W_edge, b_edge, z_n, out);
    } else {
        moon_mono<<<NBLOCKS, 256, 0, stream>>>(
            r_nb_ne, R, ne_scales, ne_kernel, ne_bias, env_weight,
            W_beta, W_gamma, W_edge, b_edge, z_n, out);
    }
}

// Round 4
// 110.266 us; speedup vs baseline: 2.6701x; 2.6701x over previous
//
#include <hip/hip_runtime.h>
#include <math.h>

#define N_NUC 256
#define N_NB  1024
#define N_ENV 8
#define F0    32
#define F1    16
#define FEAT  256
#define CUTOFF 5.0f

constexpr int NP = N_NUC * N_NB;              // 262144 pairs

__device__ __forceinline__ float rlf(float x, int i) {
    // readlane: i is wave-uniform (SGPR) or literal; result is an SGPR broadcast
    return __int_as_float(__builtin_amdgcn_readlane(__float_as_int(x), i));
}

// One pair per lane. Block = 256 threads = 4 waves = 256 pairs; 1024 blocks.
__global__ __launch_bounds__(256, 4) void moon_v4(
    const float* __restrict__ r_nb_ne,   // (256,1024,3)
    const float* __restrict__ R,         // (256,3)
    const float* __restrict__ ne_scales, // (256,8)
    const float* __restrict__ ne_kernel, // (256,4,32)
    const float* __restrict__ ne_bias,   // (256,32)
    const float* __restrict__ env_weight,// (8,32)
    const float* __restrict__ W_beta,    // (32,16)
    const float* __restrict__ W_gamma,   // (16,256)
    const float* __restrict__ W_edge,    // (4,256)
    const float* __restrict__ b_edge,    // (256)
    const float* __restrict__ z_n,       // (256,256)
    float* __restrict__ out)
{
    __shared__ float wgS[F1][FEAT];      // 16 KB: W_gamma
    __shared__ float aS[F0][16];         // 2 KB: per-k {K0,K1,K2,K3,bias,ew0..7,pad}
    __shared__ float wbS[F0][F1];        // 2 KB: W_beta

    const int tid  = threadIdx.x;
    const int lane = tid & 63;
    const int wid  = tid >> 6;
    const int n    = blockIdx.x >> 2;                    // 4 blocks per nucleus
    const int e0   = (blockIdx.x & 3) * 256 + wid * 64;  // wave's electron base
    const int pair0 = n * N_NB + e0;                     // wave's pairs: pair0 + [0,64)

    // ---- stage LDS (W_gamma vectorized; per-k table by first 32 threads) ----
    {
        const float4* src = reinterpret_cast<const float4*>(W_gamma);
        float4* dst = reinterpret_cast<float4*>(&wgS[0][0]);
        #pragma unroll
        for (int i = 0; i < 4; ++i) dst[tid + i * 256] = src[tid + i * 256];
    }
    if (tid < F0) {
        const int k = tid;
        aS[k][0] = ne_kernel[n * 128 + 0 * 32 + k];
        aS[k][1] = ne_kernel[n * 128 + 1 * 32 + k];
        aS[k][2] = ne_kernel[n * 128 + 2 * 32 + k];
        aS[k][3] = ne_kernel[n * 128 + 3 * 32 + k];
        aS[k][4] = ne_bias[n * 32 + k];
        #pragma unroll
        for (int v = 0; v < N_ENV; ++v) aS[k][5 + v] = env_weight[v * 32 + k];
        aS[k][13] = 0.f; aS[k][14] = 0.f; aS[k][15] = 0.f;
        #pragma unroll
        for (int j = 0; j < F1; ++j) wbS[k][j] = W_beta[k * F1 + j];
    }

    // ---- per-lane FEAT-slice weights (registers) ----
    const int f0 = lane * 4;
    float4 we4[4];
    #pragma unroll
    for (int c = 0; c < 4; ++c)
        we4[c] = *reinterpret_cast<const float4*>(&W_edge[c * FEAT + f0]);
    float4 zb4 = *reinterpret_cast<const float4*>(&z_n[n * FEAT + f0]);
    {
        float4 b4 = *reinterpret_cast<const float4*>(&b_edge[f0]);
        zb4.x += b4.x; zb4.y += b4.y; zb4.z += b4.z; zb4.w += b4.w;
    }

    // ---- own pair: position, distance, envelope basis, cut, inp ----
    const float Rx = R[n * 3 + 0], Ry = R[n * 3 + 1], Rz = R[n * 3 + 2];
    const size_t pr = (size_t)(pair0 + lane) * 3;
    const float dx = r_nb_ne[pr + 0] - Rx;
    const float dy = r_nb_ne[pr + 1] - Ry;
    const float dz = r_nb_ne[pr + 2] - Rz;
    const float d  = sqrtf(dx * dx + dy * dy + dz * dz);

    float E[N_ENV];
    #pragma unroll
    for (int v = 0; v < N_ENV; ++v) E[v] = __expf(-d * ne_scales[n * N_ENV + v]);

    const float xcv = d * (1.0f / CUTOFF);
    const float om  = 1.0f - xcv;
    const float cut = (xcv < 1.0f) ? om * om * (1.0f + 2.0f * xcv) : 0.0f;
    const float i0v = log1pf(d);
    const float li  = __fdividef(i0v, d);
    const float i1v = dx * li, i2v = dy * li, i3v = dz * li;

    __syncthreads();  // LDS ready

    // ---- Phase A: per-lane beta[16] over k=0..31 (all operands LDS-broadcast) ----
    float b[F1];
    #pragma unroll
    for (int j = 0; j < F1; ++j) b[j] = 0.f;

    for (int k = 0; k < F0; ++k) {
        const float4 a0 = *reinterpret_cast<const float4*>(&aS[k][0]);
        const float4 a1 = *reinterpret_cast<const float4*>(&aS[k][4]);
        const float4 a2 = *reinterpret_cast<const float4*>(&aS[k][8]);
        const float4 w0 = *reinterpret_cast<const float4*>(&wbS[k][0]);
        const float4 w1 = *reinterpret_cast<const float4*>(&wbS[k][4]);
        const float4 w2 = *reinterpret_cast<const float4*>(&wbS[k][8]);
        const float4 w3 = *reinterpret_cast<const float4*>(&wbS[k][12]);
        const float ew7 = aS[k][13 - 1];  // aS[k][12] is ew7? no: see layout below
        // layout: a0={K0,K1,K2,K3} a1={bias,ew0,ew1,ew2} a2={ew3,ew4,ew5,ew6} aS[k][12]=ew7
        const float pre = d * a0.x + dx * a0.y + dy * a0.z + dz * a0.w + a1.x;
        float env = E[0] * a1.y + E[1] * a1.z + E[2] * a1.w;
        env += E[3] * a2.x + E[4] * a2.y + E[5] * a2.z + E[6] * a2.w;
        env += E[7] * ew7;
        const float ex = __expf(2.f * pre);
        const float th = 1.f - __fdividef(2.f, ex + 1.f);
        const float h  = th * env;
        b[0]  += h * w0.x;  b[1]  += h * w0.y;  b[2]  += h * w0.z;  b[3]  += h * w0.w;
        b[4]  += h * w1.x;  b[5]  += h * w1.y;  b[6]  += h * w1.z;  b[7]  += h * w1.w;
        b[8]  += h * w2.x;  b[9]  += h * w2.y;  b[10] += h * w2.z;  b[11] += h * w2.w;
        b[12] += h * w3.x;  b[13] += h * w3.y;  b[14] += h * w3.z;  b[15] += h * w3.w;
    }
    #pragma unroll
    for (int j = 0; j < F1; ++j) b[j] *= cut;   // fold cutoff (lane-local)

    // ---- Phase B: stream 64 pairs; pair p's scalars broadcast from lane p ----
    float* __restrict__ gamma_out = out;
    float* __restrict__ edge_out  = out + (size_t)NP * FEAT;

    for (int sub = 0; sub < 8; ++sub) {
        #pragma unroll
        for (int u = 0; u < 8; ++u) {
            const int p = sub * 8 + u;           // wave-uniform lane index
            float g0 = 0.f, g1 = 0.f, g2 = 0.f, g3 = 0.f;
            #pragma unroll
            for (int j = 0; j < F1; ++j) {
                const float bj = rlf(b[j], p);
                const float4 wg = *reinterpret_cast<const float4*>(&wgS[j][f0]);
                g0 += bj * wg.x; g1 += bj * wg.y; g2 += bj * wg.z; g3 += bj * wg.w;
            }
            const float p0 = rlf(i0v, p), p1 = rlf(i1v, p);
            const float p2 = rlf(i2v, p), p3 = rlf(i3v, p);
            float4 ed;
            ed.x = p0 * we4[0].x + p1 * we4[1].x + p2 * we4[2].x + p3 * we4[3].x + zb4.x;
            ed.y = p0 * we4[0].y + p1 * we4[1].y + p2 * we4[2].y + p3 * we4[3].y + zb4.y;
            ed.z = p0 * we4[0].z + p1 * we4[1].z + p2 * we4[2].z + p3 * we4[3].z + zb4.z;
            ed.w = p0 * we4[0].w + p1 * we4[1].w + p2 * we4[2].w + p3 * we4[3].w + zb4.w;
            const size_t base = (size_t)(pair0 + p) * FEAT + f0;
            float4 gam = {g0, g1, g2, g3};
            *reinterpret_cast<float4*>(&gamma_out[base]) = gam;
            *reinterpret_cast<float4*>(&edge_out[base])  = ed;
        }
    }
}

extern "C" void kernel_launch(void* const* d_in, const int* in_sizes, int n_in,
                              void* d_out, int out_size, void* d_ws, size_t ws_size,
                              hipStream_t stream) {
    const float* r_nb_ne    = (const float*)d_in[0];
    const float* R          = (const float*)d_in[1];
    const float* ne_scales  = (const float*)d_in[2];
    const float* ne_kernel  = (const float*)d_in[3];
    const float* ne_bias    = (const float*)d_in[4];
    const float* env_weight = (const float*)d_in[5];
    const float* W_beta     = (const float*)d_in[6];
    const float* W_gamma    = (const float*)d_in[7];
    const float* W_edge     = (const float*)d_in[8];
    const float* b_edge     = (const float*)d_in[9];
    const float* z_n        = (const float*)d_in[10];
    float* out = (float*)d_out;

    moon_v4<<<NP / 256, 256, 0, stream>>>(
        r_nb_ne, R, ne_scales, ne_kernel, ne_bias, env_weight,
        W_beta, W_gamma, W_edge, b_edge, z_n, out);
}

// Round 5
// 110.001 us; speedup vs baseline: 2.6766x; 1.0024x over previous
//
#include <hip/hip_runtime.h>
#include <math.h>

#define N_NUC 256
#define N_NB  1024
#define N_ENV 8
#define F0    32
#define F1    16
#define FEAT  256
#define CUTOFF 5.0f

constexpr int NP = N_NUC * N_NB;              // 262144 pairs

__device__ __forceinline__ float rlf(float x, int i) {
    // v_readlane_b32: i is wave-uniform (SGPR or literal); SGPR broadcast result
    return __int_as_float(__builtin_amdgcn_readlane(__float_as_int(x), i));
}

// One pair per lane. Block = 256 threads = 4 waves = 256 pairs; 1024 blocks.
// Phase B processes 4 pairs per W_gamma LDS pass (amortizes ds_read_b128 4x).
__global__ __launch_bounds__(256, 4) void moon_v5(
    const float* __restrict__ r_nb_ne,   // (256,1024,3)
    const float* __restrict__ R,         // (256,3)
    const float* __restrict__ ne_scales, // (256,8)
    const float* __restrict__ ne_kernel, // (256,4,32)
    const float* __restrict__ ne_bias,   // (256,32)
    const float* __restrict__ env_weight,// (8,32)
    const float* __restrict__ W_beta,    // (32,16)
    const float* __restrict__ W_gamma,   // (16,256)
    const float* __restrict__ W_edge,    // (4,256)
    const float* __restrict__ b_edge,    // (256)
    const float* __restrict__ z_n,       // (256,256)
    float* __restrict__ out)
{
    __shared__ float wgS[F1][FEAT];      // 16 KB: W_gamma
    __shared__ float aS[F0][16];         // 2 KB: per-k {K0,K1,K2,K3,bias,ew0..7,pad3}
    __shared__ float wbS[F0][F1];        // 2 KB: W_beta

    const int tid  = threadIdx.x;
    const int lane = tid & 63;
    const int wid  = tid >> 6;
    const int n    = blockIdx.x >> 2;                    // 4 blocks per nucleus
    const int e0   = (blockIdx.x & 3) * 256 + wid * 64;  // wave's electron base
    const int pair0 = n * N_NB + e0;                     // wave's pairs: pair0 + [0,64)

    // ---- stage LDS ----
    {
        const float4* src = reinterpret_cast<const float4*>(W_gamma);
        float4* dst = reinterpret_cast<float4*>(&wgS[0][0]);
        #pragma unroll
        for (int i = 0; i < 4; ++i) dst[tid + i * 256] = src[tid + i * 256];
    }
    if (tid < F0) {
        const int k = tid;
        aS[k][0] = ne_kernel[n * 128 + 0 * 32 + k];
        aS[k][1] = ne_kernel[n * 128 + 1 * 32 + k];
        aS[k][2] = ne_kernel[n * 128 + 2 * 32 + k];
        aS[k][3] = ne_kernel[n * 128 + 3 * 32 + k];
        aS[k][4] = ne_bias[n * 32 + k];
        #pragma unroll
        for (int v = 0; v < N_ENV; ++v) aS[k][5 + v] = env_weight[v * 32 + k];
        aS[k][13] = 0.f; aS[k][14] = 0.f; aS[k][15] = 0.f;
        #pragma unroll
        for (int j = 0; j < F1; ++j) wbS[k][j] = W_beta[k * F1 + j];
    }

    // ---- per-lane FEAT-slice weights (registers) ----
    const int f0 = lane * 4;
    float4 we4[4];
    #pragma unroll
    for (int c = 0; c < 4; ++c)
        we4[c] = *reinterpret_cast<const float4*>(&W_edge[c * FEAT + f0]);
    float4 zb4 = *reinterpret_cast<const float4*>(&z_n[n * FEAT + f0]);
    {
        float4 b4 = *reinterpret_cast<const float4*>(&b_edge[f0]);
        zb4.x += b4.x; zb4.y += b4.y; zb4.z += b4.z; zb4.w += b4.w;
    }

    // ---- own pair: geometry, envelope basis, cut, inp ----
    const float Rx = R[n * 3 + 0], Ry = R[n * 3 + 1], Rz = R[n * 3 + 2];
    const size_t pr = (size_t)(pair0 + lane) * 3;
    const float dx = r_nb_ne[pr + 0] - Rx;
    const float dy = r_nb_ne[pr + 1] - Ry;
    const float dz = r_nb_ne[pr + 2] - Rz;
    const float d  = sqrtf(dx * dx + dy * dy + dz * dz);

    float E[N_ENV];
    #pragma unroll
    for (int v = 0; v < N_ENV; ++v) E[v] = __expf(-d * ne_scales[n * N_ENV + v]);

    const float xcv = d * (1.0f / CUTOFF);
    const float om  = 1.0f - xcv;
    const float cut = (xcv < 1.0f) ? om * om * (1.0f + 2.0f * xcv) : 0.0f;
    const float i0v = log1pf(d);
    const float li  = __fdividef(i0v, d);
    const float i1v = dx * li, i2v = dy * li, i3v = dz * li;

    __syncthreads();  // LDS ready

    // ---- Phase A: per-lane beta[16] over k (all weight operands LDS-broadcast) ----
    float b[F1];
    #pragma unroll
    for (int j = 0; j < F1; ++j) b[j] = 0.f;

    for (int k = 0; k < F0; ++k) {
        const float4 a0 = *reinterpret_cast<const float4*>(&aS[k][0]);
        const float4 a1 = *reinterpret_cast<const float4*>(&aS[k][4]);
        const float4 a2 = *reinterpret_cast<const float4*>(&aS[k][8]);
        const float ew7 = aS[k][12];
        const float4 w0 = *reinterpret_cast<const float4*>(&wbS[k][0]);
        const float4 w1 = *reinterpret_cast<const float4*>(&wbS[k][4]);
        const float4 w2 = *reinterpret_cast<const float4*>(&wbS[k][8]);
        const float4 w3 = *reinterpret_cast<const float4*>(&wbS[k][12]);
        const float pre = d * a0.x + dx * a0.y + dy * a0.z + dz * a0.w + a1.x;
        float env = E[0] * a1.y + E[1] * a1.z + E[2] * a1.w;
        env += E[3] * a2.x + E[4] * a2.y + E[5] * a2.z + E[6] * a2.w;
        env += E[7] * ew7;
        const float ex = __expf(2.f * pre);
        const float th = 1.f - __fdividef(2.f, ex + 1.f);
        const float h  = th * env;
        b[0]  += h * w0.x;  b[1]  += h * w0.y;  b[2]  += h * w0.z;  b[3]  += h * w0.w;
        b[4]  += h * w1.x;  b[5]  += h * w1.y;  b[6]  += h * w1.z;  b[7]  += h * w1.w;
        b[8]  += h * w2.x;  b[9]  += h * w2.y;  b[10] += h * w2.z;  b[11] += h * w2.w;
        b[12] += h * w3.x;  b[13] += h * w3.y;  b[14] += h * w3.z;  b[15] += h * w3.w;
    }
    #pragma unroll
    for (int j = 0; j < F1; ++j) b[j] *= cut;

    // ---- Phase B: 16 groups x 4 pairs; one W_gamma LDS pass per group ----
    float* __restrict__ gamma_out = out;
    float* __restrict__ edge_out  = out + (size_t)NP * FEAT;

    for (int grp = 0; grp < 16; ++grp) {
        const int p0 = grp * 4;                  // wave-uniform
        float4 g0 = {0,0,0,0}, g1 = {0,0,0,0}, g2 = {0,0,0,0}, g3 = {0,0,0,0};
        #pragma unroll
        for (int j = 0; j < F1; ++j) {
            const float4 wg = *reinterpret_cast<const float4*>(&wgS[j][f0]);
            const float bj0 = rlf(b[j], p0 + 0);
            const float bj1 = rlf(b[j], p0 + 1);
            const float bj2 = rlf(b[j], p0 + 2);
            const float bj3 = rlf(b[j], p0 + 3);
            g0.x += bj0 * wg.x; g0.y += bj0 * wg.y; g0.z += bj0 * wg.z; g0.w += bj0 * wg.w;
            g1.x += bj1 * wg.x; g1.y += bj1 * wg.y; g1.z += bj1 * wg.z; g1.w += bj1 * wg.w;
            g2.x += bj2 * wg.x; g2.y += bj2 * wg.y; g2.z += bj2 * wg.z; g2.w += bj2 * wg.w;
            g3.x += bj3 * wg.x; g3.y += bj3 * wg.y; g3.z += bj3 * wg.z; g3.w += bj3 * wg.w;
        }
        #pragma unroll
        for (int q = 0; q < 4; ++q) {
            const int p = p0 + q;
            const float e0s = rlf(i0v, p), e1s = rlf(i1v, p);
            const float e2s = rlf(i2v, p), e3s = rlf(i3v, p);
            float4 ed;
            ed.x = e0s * we4[0].x + e1s * we4[1].x + e2s * we4[2].x + e3s * we4[3].x + zb4.x;
            ed.y = e0s * we4[0].y + e1s * we4[1].y + e2s * we4[2].y + e3s * we4[3].y + zb4.y;
            ed.z = e0s * we4[0].z + e1s * we4[1].z + e2s * we4[2].z + e3s * we4[3].z + zb4.z;
            ed.w = e0s * we4[0].w + e1s * we4[1].w + e2s * we4[2].w + e3s * we4[3].w + zb4.w;
            const float4 gq = (q == 0) ? g0 : (q == 1) ? g1 : (q == 2) ? g2 : g3;
            const size_t base = (size_t)(pair0 + p) * FEAT + f0;
            *reinterpret_cast<float4*>(&gamma_out[base]) = gq;
            *reinterpret_cast<float4*>(&edge_out[base])  = ed;
        }
    }
}

extern "C" void kernel_launch(void* const* d_in, const int* in_sizes, int n_in,
                              void* d_out, int out_size, void* d_ws, size_t ws_size,
                              hipStream_t stream) {
    const float* r_nb_ne    = (const float*)d_in[0];
    const float* R          = (const float*)d_in[1];
    const float* ne_scales  = (const float*)d_in[2];
    const float* ne_kernel  = (const float*)d_in[3];
    const float* ne_bias    = (const float*)d_in[4];
    const float* env_weight = (const float*)d_in[5];
    const float* W_beta     = (const float*)d_in[6];
    const float* W_gamma    = (const float*)d_in[7];
    const float* W_edge     = (const float*)d_in[8];
    const float* b_edge     = (const float*)d_in[9];
    const float* z_n        = (const float*)d_in[10];
    float* out = (float*)d_out;

    moon_v5<<<NP / 256, 256, 0, stream>>>(
        r_nb_ne, R, ne_scales, ne_kernel, ne_bias, env_weight,
        W_beta, W_gamma, W_edge, b_edge, z_n, out);
}